// Round 6
// baseline (89.331 us; speedup 1.0000x reference)
//
#include <hip/hip_runtime.h>
#include <hip/hip_bf16.h>
#include <hip/hip_fp16.h>

typedef _Float16 half8_t  __attribute__((ext_vector_type(8)));
typedef short    short8_t __attribute__((ext_vector_type(8)));
typedef short    short4_t __attribute__((ext_vector_type(4)));
typedef float    f32x4    __attribute__((ext_vector_type(4)));

#define LOG2E 1.44269504088896f

__device__ __forceinline__ unsigned pack_bf16_2(float lo, float hi) {
  float2 f2; f2.x = lo; f2.y = hi;
  __hip_bfloat162 h2 = __float22bfloat162_rn(f2);
  return *reinterpret_cast<unsigned*>(&h2);
}

// ---------------------------------------------------------------------------
// Kernel 1 (v10): MFMA prep, 8-wave split + float4 Wh staging.
// One block = 64 positions, 512 threads. Wave (wr, half): wr = wv&3 row-tile,
// half 0 -> nt 0..2, half 1 -> nt 3..4. Outputs attn's exact layouts:
// f key-permuted slots, g (x log2e), vT bf16.
// ---------------------------------------------------------------------------
__global__ __launch_bounds__(512) void prep_kernel(
    const float* __restrict__ x,
    const float* __restrict__ Wf, const float* __restrict__ bf,
    const float* __restrict__ Wg, const float* __restrict__ bg,
    const float* __restrict__ Wh, const float* __restrict__ bh,
    _Float16* __restrict__ fh, _Float16* __restrict__ gh,
    unsigned short* __restrict__ vT)
{
  __shared__ _Float16 WtT[80 * 72];   // [ch][c], stride 72
  __shared__ float ball[80];
  const int t = threadIdx.x;

  {
    int c = t >> 3, d = t & 7;       // 512 threads cover Wf/Wg in one pass
    WtT[d * 72 + c]       = (_Float16)Wf[t];
    WtT[(8 + d) * 72 + c] = (_Float16)(Wg[t] * LOG2E);
  }
  // Wh: 4096 f32 = 1024 float4; 512 threads x 2 vector loads
#pragma unroll
  for (int rep = 0; rep < 2; rep++) {
    int i4 = t + rep * 512;
    float4 wv4 = *(const float4*)(Wh + i4 * 4);
    int c  = i4 >> 4;            // (i4*4)/64
    int ch = (i4 & 15) * 4;      // (i4*4)%64
    WtT[(16 + ch + 0) * 72 + c] = (_Float16)wv4.x;
    WtT[(16 + ch + 1) * 72 + c] = (_Float16)wv4.y;
    WtT[(16 + ch + 2) * 72 + c] = (_Float16)wv4.z;
    WtT[(16 + ch + 3) * 72 + c] = (_Float16)wv4.w;
  }
  if (t < 80) ball[t] = (t < 8) ? bf[t] : (t < 16) ? bg[t - 8] * LOG2E : bh[t - 16];
  __syncthreads();

  const int lane = t & 63, wv = t >> 6;
  const int quad = lane >> 4, l15 = lane & 15;
  const int wr   = wv & 3;       // row tile
  const int hsel = wv >> 2;      // 0: nt 0..2, 1: nt 3..4
  const int p0  = blockIdx.x * 64;
  const int row = p0 + wr * 16 + l15;

  const float* xr = x + (size_t)row * 64 + quad * 8;
  float4 xa = *(const float4*)(xr);
  float4 xb = *(const float4*)(xr + 4);
  float4 xc = *(const float4*)(xr + 32);
  float4 xd = *(const float4*)(xr + 36);
  half8_t a0, a1;
  a0[0]=(_Float16)xa.x; a0[1]=(_Float16)xa.y; a0[2]=(_Float16)xa.z; a0[3]=(_Float16)xa.w;
  a0[4]=(_Float16)xb.x; a0[5]=(_Float16)xb.y; a0[6]=(_Float16)xb.z; a0[7]=(_Float16)xb.w;
  a1[0]=(_Float16)xc.x; a1[1]=(_Float16)xc.y; a1[2]=(_Float16)xc.z; a1[3]=(_Float16)xc.w;
  a1[4]=(_Float16)xd.x; a1[5]=(_Float16)xd.y; a1[6]=(_Float16)xd.z; a1[7]=(_Float16)xd.w;

  const f32x4 zc = {0.f, 0.f, 0.f, 0.f};
  const int b     = p0 >> 12;
  const int nbase = (p0 & 4095) + wr * 16 + quad * 4;
  const int kblock = nbase >> 5;
  const int r0     = nbase & 31;
  const int q8 = r0 >> 3, j8 = r0 & 7;
  const int slot0 = (j8 < 4) ? (q8 * 4 + j8) : (16 + q8 * 4 + (j8 - 4));
  const size_t fbase_out = ((size_t)b * 4096 + (kblock << 5) + slot0) * 8;
  const size_t gbase_out = ((size_t)p0 + wr * 16 + quad * 4) * 8;
  const size_t vbase_out = (((size_t)b * 128 + kblock) << 11) + r0;

  if (hsel == 0) {
    // nt = 0: f (ch 0-7) / g (ch 8-15)
    {
      const _Float16* wt = &WtT[l15 * 72 + quad * 8];
      half8_t b0 = *(const half8_t*)(wt);
      half8_t b1 = *(const half8_t*)(wt + 32);
      f32x4 d = __builtin_amdgcn_mfma_f32_16x16x32_f16(a0, b0, zc, 0, 0, 0);
      d = __builtin_amdgcn_mfma_f32_16x16x32_f16(a1, b1, d, 0, 0, 0);
      const float bias = ball[l15];
      if (l15 < 8) {
#pragma unroll
        for (int reg = 0; reg < 4; reg++)
          fh[fbase_out + (size_t)reg * 8 + l15] = (_Float16)(d[reg] + bias);
      } else {
#pragma unroll
        for (int reg = 0; reg < 4; reg++)
          gh[gbase_out + (size_t)reg * 8 + (l15 - 8)] = (_Float16)(d[reg] + bias);
      }
    }
#pragma unroll
    for (int nt = 1; nt < 3; nt++) {
      const int ch0 = nt * 16 + l15;
      const _Float16* wt = &WtT[ch0 * 72 + quad * 8];
      half8_t b0 = *(const half8_t*)(wt);
      half8_t b1 = *(const half8_t*)(wt + 32);
      f32x4 d = __builtin_amdgcn_mfma_f32_16x16x32_f16(a0, b0, zc, 0, 0, 0);
      d = __builtin_amdgcn_mfma_f32_16x16x32_f16(a1, b1, d, 0, 0, 0);
      const float bias = ball[ch0];
      const int vch = ch0 - 16;
      union { unsigned u[2]; short4_t s; } pk;
      pk.u[0] = pack_bf16_2(d[0] + bias, d[1] + bias);
      pk.u[1] = pack_bf16_2(d[2] + bias, d[3] + bias);
      *(short4_t*)(vT + vbase_out + (size_t)vch * 32) = pk.s;
    }
  } else {
#pragma unroll
    for (int nt = 3; nt < 5; nt++) {
      const int ch0 = nt * 16 + l15;
      const _Float16* wt = &WtT[ch0 * 72 + quad * 8];
      half8_t b0 = *(const half8_t*)(wt);
      half8_t b1 = *(const half8_t*)(wt + 32);
      f32x4 d = __builtin_amdgcn_mfma_f32_16x16x32_f16(a0, b0, zc, 0, 0, 0);
      d = __builtin_amdgcn_mfma_f32_16x16x32_f16(a1, b1, d, 0, 0, 0);
      const float bias = ball[ch0];
      const int vch = ch0 - 16;
      union { unsigned u[2]; short4_t s; } pk;
      pk.u[0] = pack_bf16_2(d[0] + bias, d[1] + bias);
      pk.u[1] = pack_bf16_2(d[2] + bias, d[3] + bias);
      *(short4_t*)(vT + vbase_out + (size_t)vch * 32) = pk.s;
    }
  }
}

// ---------------------------------------------------------------------------
// Kernel 2 (v19): v18 + (a) TWIN-WAVE PHASE OFFSET: waves w and w+4 share a
// SIMD and run identical instruction streams -> they stall on the same
// s_waitcnt simultaneously (explains occupancy/prefetch-insensitivity).
// Chunk visit order now rotated by (w>>2)*8 so SIMD-twins are 8 chunks
// apart in program phase; one covers the other's L2 stalls.
// (b) sched_barrier(0) after the prefetch cluster: stops the compiler
// sinking "prefetch" loads back to their uses (suspected cause of r5's
// null). (c) s_setprio(1) around the MFMA/exp cluster (T5).
// ---------------------------------------------------------------------------
__device__ __forceinline__ void compute_chunk(
    const half8_t& f0, const half8_t& f1,
    const short8_t& v0, const short8_t& v1,
    const short8_t& v2, const short8_t& v3,
    const half8_t (&gfrag)[4], const short8_t& ones8,
    f32x4 (&acc)[4][4], f32x4 (&acc4)[4])
{
  const f32x4 zc = {0.f, 0.f, 0.f, 0.f};
  __builtin_amdgcn_s_setprio(1);
#pragma unroll
  for (int tt = 0; tt < 4; tt++) {
    f32x4 s0 = __builtin_amdgcn_mfma_f32_16x16x32_f16(f0, gfrag[tt], zc, 0, 0, 0);
    f32x4 s1 = __builtin_amdgcn_mfma_f32_16x16x32_f16(f1, gfrag[tt], zc, 0, 0, 0);
    float p00 = __builtin_amdgcn_exp2f(s0[0]), p01 = __builtin_amdgcn_exp2f(s0[1]);
    float p02 = __builtin_amdgcn_exp2f(s0[2]), p03 = __builtin_amdgcn_exp2f(s0[3]);
    float p10 = __builtin_amdgcn_exp2f(s1[0]), p11 = __builtin_amdgcn_exp2f(s1[1]);
    float p12 = __builtin_amdgcn_exp2f(s1[2]), p13 = __builtin_amdgcn_exp2f(s1[3]);
    union { unsigned u[4]; short8_t v; } pu;
    pu.u[0] = pack_bf16_2(p00, p01);
    pu.u[1] = pack_bf16_2(p02, p03);
    pu.u[2] = pack_bf16_2(p10, p11);
    pu.u[3] = pack_bf16_2(p12, p13);
    short8_t pfrag = pu.v;
    acc[tt][0] = __builtin_amdgcn_mfma_f32_16x16x32_bf16(v0, pfrag, acc[tt][0], 0, 0, 0);
    acc[tt][1] = __builtin_amdgcn_mfma_f32_16x16x32_bf16(v1, pfrag, acc[tt][1], 0, 0, 0);
    acc[tt][2] = __builtin_amdgcn_mfma_f32_16x16x32_bf16(v2, pfrag, acc[tt][2], 0, 0, 0);
    acc[tt][3] = __builtin_amdgcn_mfma_f32_16x16x32_bf16(v3, pfrag, acc[tt][3], 0, 0, 0);
    acc4[tt]   = __builtin_amdgcn_mfma_f32_16x16x32_bf16(ones8, pfrag, acc4[tt], 0, 0, 0);
  }
  __builtin_amdgcn_s_setprio(0);
}

__global__ __launch_bounds__(512, 2) void attn_kernel(
    const _Float16* __restrict__ fh,        // [B][N][8] f16, key-permuted slots
    const _Float16* __restrict__ gh,        // [B][N][8] f16 (x log2e)
    const unsigned short* __restrict__ vT,  // [b][kblock][ch][r] bf16
    float* __restrict__ out)                // [B][N][64] f32
{
  const int N    = 4096;
  const int lane = threadIdx.x & 63;
  const int w    = threadIdx.x >> 6;       // 0..7 = key range
  const int quad = lane >> 4;
  const int l15  = lane & 15;

  __shared__ float red[7][64][17];

  const int xcd = blockIdx.x & 7;
  const int b   = xcd >> 1;
  const int qg  = ((blockIdx.x >> 3) << 1) + (xcd & 1);  // 0..63
  const int q0  = qg * 64;
  const int kbase = w * 512;
  // stagger: de-correlate L2 streams across blocks (phase) AND de-phase
  // SIMD-twin waves w / w+4 within a block ((w>>2)*8)
  const int rot = ((qg >> 1) & 15) + ((w >> 2) << 3);

  const _Float16* fbase = fh + (size_t)b * N * 8;
  const _Float16* gbase = gh + (size_t)b * N * 8;
  const short*    vbat  = (const short*)vT + (size_t)b * 262144 + (l15 << 5) + (quad << 3);

  half8_t gfrag[4] = {{}, {}, {}, {}};
  if (quad == 0) {
#pragma unroll
    for (int tt = 0; tt < 4; tt++)
      gfrag[tt] = *(const half8_t*)(gbase + (size_t)(q0 + tt * 16 + l15) * 8);
  }

  const f32x4 zc = {0.f, 0.f, 0.f, 0.f};
  f32x4 acc[4][4];
  f32x4 acc4[4];
#pragma unroll
  for (int tt = 0; tt < 4; tt++) {
    acc4[tt] = zc;
#pragma unroll
    for (int ct = 0; ct < 4; ct++) acc[tt][ct] = zc;
  }

  short8_t ones8;
#pragma unroll
  for (int i = 0; i < 8; i++) ones8[i] = (short)0x3F80;

#define KOFF(j) (kbase + ((((j) + rot) & 15) << 5))
#define LOADC(k, F0, F1, V0, V1, V2, V3)                                  \
  {                                                                       \
    const int kk = (k);                                                   \
    if (quad == 0) {                                                      \
      F0 = *(const half8_t*)(fbase + (size_t)(kk + l15) * 8);             \
      F1 = *(const half8_t*)(fbase + (size_t)(kk + 16 + l15) * 8);        \
    }                                                                     \
    const short* vk = vbat + ((size_t)(kk >> 5) << 11);                   \
    V0 = *(const short8_t*)(vk);                                          \
    V1 = *(const short8_t*)(vk + 512);                                    \
    V2 = *(const short8_t*)(vk + 1024);                                   \
    V3 = *(const short8_t*)(vk + 1536);                                   \
  }

  // 4 chunk-buffers A,B,C,D
  half8_t  fA0 = {}, fA1 = {}, fB0 = {}, fB1 = {};
  half8_t  fC0 = {}, fC1 = {}, fD0 = {}, fD1 = {};
  short8_t vA0, vA1, vA2, vA3, vB0, vB1, vB2, vB3;
  short8_t vC0, vC1, vC2, vC3, vD0, vD1, vD2, vD3;

  LOADC(KOFF(0), fA0, fA1, vA0, vA1, vA2, vA3);
  LOADC(KOFF(1), fB0, fB1, vB0, vB1, vB2, vB3);

#pragma unroll 1
  for (int cc = 0; cc < 16; cc += 4) {
    LOADC(KOFF(cc + 2), fC0, fC1, vC0, vC1, vC2, vC3);
    LOADC(KOFF(cc + 3), fD0, fD1, vD0, vD1, vD2, vD3);
    __builtin_amdgcn_sched_barrier(0);   // pin prefetch issue point
    compute_chunk(fA0, fA1, vA0, vA1, vA2, vA3, gfrag, ones8, acc, acc4);
    compute_chunk(fB0, fB1, vB0, vB1, vB2, vB3, gfrag, ones8, acc, acc4);
    if (cc + 4 < 16) {
      LOADC(KOFF(cc + 4), fA0, fA1, vA0, vA1, vA2, vA3);
      LOADC(KOFF(cc + 5), fB0, fB1, vB0, vB1, vB2, vB3);
      __builtin_amdgcn_sched_barrier(0); // pin prefetch issue point
    }
    compute_chunk(fC0, fC1, vC0, vC1, vC2, vC3, gfrag, ones8, acc, acc4);
    compute_chunk(fD0, fD1, vD0, vD1, vD2, vD3, gfrag, ones8, acc, acc4);
  }
#undef LOADC
#undef KOFF

  // ---- cross-wave combine: fully unrolled (static acc indices), in-place
  // accumulation, stores deferred past last barrier ----
#pragma unroll
  for (int tt = 0; tt < 4; tt++) {
    if (w > 0) {
      float* p = &red[w - 1][lane][0];
#pragma unroll
      for (int ct = 0; ct < 4; ct++)
#pragma unroll
        for (int reg = 0; reg < 4; reg++) p[ct * 4 + reg] = acc[tt][ct][reg];
      p[16] = acc4[tt][0];
    }
    __syncthreads();
    if (w == 0) {
#pragma unroll
      for (int ww = 0; ww < 7; ww++) {
        const float* p = &red[ww][lane][0];
#pragma unroll
        for (int reg = 0; reg < 4; reg++) {
          acc[tt][0][reg] += p[0 + reg];
          acc[tt][1][reg] += p[4 + reg];
          acc[tt][2][reg] += p[8 + reg];
          acc[tt][3][reg] += p[12 + reg];
        }
        acc4[tt][0] += p[16];
      }
    }
    if (tt < 3) __syncthreads();
  }

  if (w == 0) {
#pragma unroll
    for (int tt = 0; tt < 4; tt++) {
      const float inv = 1.0f / acc4[tt][0];
      float* ob = out + ((size_t)b * N + q0 + tt * 16 + l15) * 64 + (quad << 2);
      *(f32x4*)(ob)      = acc[tt][0] * inv;
      *(f32x4*)(ob + 16) = acc[tt][1] * inv;
      *(f32x4*)(ob + 32) = acc[tt][2] * inv;
      *(f32x4*)(ob + 48) = acc[tt][3] * inv;
    }
  }
}

// ---------------------------------------------------------------------------
extern "C" void kernel_launch(void* const* d_in, const int* in_sizes, int n_in,
                              void* d_out, int out_size, void* d_ws, size_t ws_size,
                              hipStream_t stream) {
  const float* x  = (const float*)d_in[0];
  const float* Wf = (const float*)d_in[1];
  const float* bf = (const float*)d_in[2];
  const float* Wg = (const float*)d_in[3];
  const float* bg = (const float*)d_in[4];
  const float* Wh = (const float*)d_in[5];
  const float* bh = (const float*)d_in[6];
  float* out = (float*)d_out;

  char* ws = (char*)d_ws;
  _Float16* fh = (_Float16*)ws;                        // 256 KB
  _Float16* gh = (_Float16*)(ws + 262144);             // 256 KB
  unsigned short* vT = (unsigned short*)(ws + 524288); // 2 MB

  prep_kernel<<<256, 512, 0, stream>>>(x, Wf, bf, Wg, bg, Wh, bh, fh, gh, vT);
  attn_kernel<<<256, 512, 0, stream>>>(fh, gh, vT, out);
}